// Round 7
// baseline (992.055 us; speedup 1.0000x reference)
//
#include <hip/hip_runtime.h>

#define N_PTS  4096
#define N_CENT 1024
#define K_S    32
#define EPSV   1e-5f

typedef __attribute__((ext_vector_type(8))) short short8;
typedef __attribute__((ext_vector_type(4))) float floatx4;
typedef __attribute__((ext_vector_type(2))) float float2v;

// Manual bf16 RNE (round-to-nearest-even), same as __float2bfloat16_rn for
// finite inputs; avoids the non-trivially-copyable __hip_bfloat162 class.
__device__ inline unsigned short bf1(float x) {
  unsigned u = __float_as_uint(x);
  u += 0x7fffu + ((u >> 16) & 1u);
  return (unsigned short)(u >> 16);
}
__device__ inline unsigned pkbf(float a, float b) {
  return (unsigned)bf1(a) | ((unsigned)bf1(b) << 16);
}

// ws byte layout:
//   0     : WB0 bf16 [64 o][96 k]   (k 0..63 = points ch, 64..66 = xyz, 67..95 = 0)
//   12288 : WB1 bf16 [64 o][64 k]
//   20480 : WB2 bf16 [128 o][64 k]
//   36864 : Bf0 f32[64]   37120: Bf1 f32[64]   37376: Bf2 f32[128]
__global__ void prep_kernel(const float* __restrict__ W0, const float* __restrict__ b0,
                            const float* __restrict__ g0, const float* __restrict__ be0,
                            const float* __restrict__ m0, const float* __restrict__ v0,
                            const float* __restrict__ W1, const float* __restrict__ b1,
                            const float* __restrict__ g1, const float* __restrict__ be1,
                            const float* __restrict__ m1, const float* __restrict__ v1,
                            const float* __restrict__ W2, const float* __restrict__ b2,
                            const float* __restrict__ g2, const float* __restrict__ be2,
                            const float* __restrict__ m2, const float* __restrict__ v2,
                            unsigned char* __restrict__ wsb) {
  const int stride = gridDim.x * blockDim.x;
  const int tid = blockIdx.x * blockDim.x + threadIdx.x;
  unsigned short* WB0 = (unsigned short*)wsb;
  unsigned short* WB1 = (unsigned short*)(wsb + 12288);
  unsigned short* WB2 = (unsigned short*)(wsb + 20480);
  float* Bf0 = (float*)(wsb + 36864);
  float* Bf1 = (float*)(wsb + 37120);
  float* Bf2 = (float*)(wsb + 37376);
  for (int i = tid; i < 64 * 96; i += stride) {
    int o = i / 96, k = i - o * 96;
    float s = g0[o] * rsqrtf(v0[o] + EPSV);
    float val = 0.0f;
    if (k < 64) val = W0[o * 67 + 3 + k] * s;
    else if (k < 67) val = W0[o * 67 + (k - 64)] * s;
    WB0[i] = bf1(val);
  }
  for (int i = tid; i < 64; i += stride) {
    float s = g0[i] * rsqrtf(v0[i] + EPSV);
    Bf0[i] = (b0[i] - m0[i]) * s + be0[i];
  }
  for (int i = tid; i < 64 * 64; i += stride) {
    int o = i >> 6;
    float s = g1[o] * rsqrtf(v1[o] + EPSV);
    WB1[i] = bf1(W1[i] * s);
  }
  for (int i = tid; i < 64; i += stride) {
    float s = g1[i] * rsqrtf(v1[i] + EPSV);
    Bf1[i] = (b1[i] - m1[i]) * s + be1[i];
  }
  for (int i = tid; i < 128 * 64; i += stride) {
    int o = i >> 6;
    float s = g2[o] * rsqrtf(v2[o] + EPSV);
    WB2[i] = bf1(W2[i] * s);
  }
  for (int i = tid; i < 128; i += stride) {
    float s = g2[i] * rsqrtf(v2[i] + EPSV);
    Bf2[i] = (b2[i] - m2[i]) * s + be2[i];
  }
}

// ---------------- FPS: one block (512 thr, 8 waves) per batch ----------------
// Packed u64 key = (fp32 bits of dist << 32) | ~idx  — positive floats are
// monotone as uints, so max(key) == (max dist, tie -> smaller idx).
// Distance updates use packed fp32 (v_pk_sub/mul/add) — per-lane results are
// bit-identical to scalar contract(off) ops, so the index sequence is exact.
#define DPP_STEP(CTRL)                                                               \
  {                                                                                  \
    unsigned lo2 = (unsigned)__builtin_amdgcn_update_dpp(                            \
        0, (int)(unsigned)key, (CTRL), 0xf, 0xf, false);                             \
    unsigned hi2 = (unsigned)__builtin_amdgcn_update_dpp(                            \
        0, (int)(unsigned)(key >> 32), (CTRL), 0xf, 0xf, false);                     \
    unsigned long long nk = ((unsigned long long)hi2 << 32) | lo2;                   \
    if (nk > key) key = nk;                                                          \
  }

__launch_bounds__(512)
__global__ void fps_kernel(const float* __restrict__ xyz, float* __restrict__ new_xyz) {
#pragma clang fp contract(off)
  const int b = blockIdx.x;
  const int tid = threadIdx.x;
  const int lane = tid & 63, wv = tid >> 6;
  const float* X = xyz + (size_t)b * N_PTS * 3;
  __shared__ float lx[N_PTS], ly[N_PTS], lz[N_PTS];
  __shared__ float cent[N_CENT * 3];
  __shared__ unsigned long long rkey[2][8];
  float2v px[4], py[4], pz[4], dist[4];
#pragma unroll
  for (int j = 0; j < 8; ++j) {
    int p = j * 512 + tid;
    float x = X[p * 3 + 0], y = X[p * 3 + 1], z = X[p * 3 + 2];
    lx[p] = x; ly[p] = y; lz[p] = z;
    int t = j >> 1;
    if ((j & 1) == 0) { px[t].x = x; py[t].x = y; pz[t].x = z; dist[t].x = 1e10f; }
    else              { px[t].y = x; py[t].y = y; pz[t].y = z; dist[t].y = 1e10f; }
  }
  if (tid == 0) { cent[0] = X[0]; cent[1] = X[1]; cent[2] = X[2]; }
  __syncthreads();
  int far = 0;
  for (int i = 1; i < N_CENT; ++i) {
    float cx = lx[far], cy = ly[far], cz = lz[far];
    float2v cx2 = {cx, cx}, cy2 = {cy, cy}, cz2 = {cz, cz};
    float best = -1.0f;
    int bi = 0;
#pragma unroll
    for (int t = 0; t < 4; ++t) {
      float2v dx = px[t] - cx2, dy = py[t] - cy2, dz = pz[t] - cz2;
      float2v d2 = dx * dx + dy * dy + dz * dz;  // pk math, contract off
      float d0 = fminf(dist[t].x, d2.x); dist[t].x = d0;
      if (d0 > best) { best = d0; bi = (2 * t) * 512 + tid; }
      float d1 = fminf(dist[t].y, d2.y); dist[t].y = d1;
      if (d1 > best) { best = d1; bi = (2 * t + 1) * 512 + tid; }
    }
    unsigned long long key =
        ((unsigned long long)__float_as_uint(best) << 32) | (unsigned)(~bi);
    DPP_STEP(0x111);  // row_shr:1
    DPP_STEP(0x112);  // row_shr:2
    DPP_STEP(0x114);  // row_shr:4
    DPP_STEP(0x118);  // row_shr:8
    DPP_STEP(0x142);  // row_bcast15
    DPP_STEP(0x143);  // row_bcast31 -> lane 63 has wave winner
    const int par = i & 1;
    if (lane == 63) rkey[par][wv] = key;
    __syncthreads();
    unsigned long long k0 = rkey[par][0], k1 = rkey[par][1];
    unsigned long long k2 = rkey[par][2], k3 = rkey[par][3];
    unsigned long long k4 = rkey[par][4], k5 = rkey[par][5];
    unsigned long long k6 = rkey[par][6], k7 = rkey[par][7];
    if (k1 > k0) k0 = k1;
    if (k3 > k2) k2 = k3;
    if (k5 > k4) k4 = k5;
    if (k7 > k6) k6 = k7;
    if (k2 > k0) k0 = k2;
    if (k6 > k4) k4 = k6;
    if (k4 > k0) k0 = k4;
    far = (int)~(unsigned)k0;
    if (tid == 0) {
      cent[i * 3 + 0] = lx[far];
      cent[i * 3 + 1] = ly[far];
      cent[i * 3 + 2] = lz[far];
    }
  }
  __syncthreads();
  const size_t ob = (size_t)b * N_CENT * 3;
  for (int t = tid; t < N_CENT * 3; t += 512) new_xyz[ob + t] = cent[t];
}

// ------- fused ball-query + gather + 3-layer bf16-MFMA MLP + maxpool -------
// 256 thr = 4 waves; 8 centroids x 32 samples = 256 points per block.
// h LDS rows: 96 bf16 K-channels (+8 pad) = 208 B stride.
__launch_bounds__(256)
__global__ void mlp_kernel(const float* __restrict__ xyz,
                           const float* __restrict__ points,
                           const float* __restrict__ new_xyz,
                           const unsigned char* __restrict__ wsb,
                           float* __restrict__ out_pts) {
  __shared__ int nidx[256];
  __shared__ __align__(16) unsigned short h[256 * 104];
  const int blk = blockIdx.x;
  const int b = blk >> 7;
  const int s0 = (blk & 127) << 3;
  const int tid = threadIdx.x;
  const float* Xb = xyz + (size_t)b * N_PTS * 3;

  // ---- phase 1: ball query — both centroids of the wave tested per chunk
  //      (halves the serial chain depth; d2 decisions bit-identical to R6) ----
  {
#pragma clang fp contract(off)
    const int wv = tid >> 6, lane = tid & 63;
    const float r2 = (float)(0.2 * 0.2);
    const int sA = s0 + wv * 2, sB = sA + 1;
    float cxA = new_xyz[((size_t)b * N_CENT + sA) * 3 + 0];
    float cyA = new_xyz[((size_t)b * N_CENT + sA) * 3 + 1];
    float czA = new_xyz[((size_t)b * N_CENT + sA) * 3 + 2];
    float cxB = new_xyz[((size_t)b * N_CENT + sB) * 3 + 0];
    float cyB = new_xyz[((size_t)b * N_CENT + sB) * 3 + 1];
    float czB = new_xyz[((size_t)b * N_CENT + sB) * 3 + 2];
    float scA = cxA * cxA + cyA * cyA + czA * czA;
    float scB = cxB * cxB + cyB * cyB + czB * czB;
    int cntA = 0, cntB = 0, firstA = 0, firstB = 0;
    for (int base = 0; base < N_PTS && (cntA < K_S || cntB < K_S); base += 64) {
      int p = base + lane;
      float x = Xb[p * 3 + 0], y = Xb[p * 3 + 1], z = Xb[p * 3 + 2];
      float sp = x * x + y * y + z * z;
      float dtA = __builtin_fmaf(czA, z, __builtin_fmaf(cyA, y, cxA * x));
      float dtB = __builtin_fmaf(czB, z, __builtin_fmaf(cyB, y, cxB * x));
      float d2A = (scA + sp) - 2.0f * dtA;
      float d2B = (scB + sp) - 2.0f * dtB;
      bool inA = !(d2A > r2);
      bool inB = !(d2B > r2);
      unsigned long long mA = __ballot(inA);
      unsigned long long mB = __ballot(inB);
      if (cntA == 0 && mA != 0ull) firstA = base + __builtin_ctzll(mA);
      if (cntB == 0 && mB != 0ull) firstB = base + __builtin_ctzll(mB);
      unsigned long long below = (1ull << lane) - 1ull;
      int posA = cntA + __popcll(mA & below);
      int posB = cntB + __popcll(mB & below);
      if (inA && posA < K_S) nidx[(wv * 2 + 0) * K_S + posA] = p;
      if (inB && posB < K_S) nidx[(wv * 2 + 1) * K_S + posB] = p;
      cntA += __popcll(mA);
      cntB += __popcll(mB);
    }
    if (cntA < K_S)
      for (int j = cntA + lane; j < K_S; j += 64) nidx[(wv * 2 + 0) * K_S + j] = firstA;
    if (cntB < K_S)
      for (int j = cntB + lane; j < K_S; j += 64) nidx[(wv * 2 + 1) * K_S + j] = firstB;
  }
  __syncthreads();

  // ---- phase 2: gather -> h rows (bf16): k0..63 = points, 64..66 = xyz, rest 0
  {
    const int s = s0 + (tid >> 5);
    const int id = nidx[tid];
    float cx = new_xyz[((size_t)b * N_CENT + s) * 3 + 0];
    float cy = new_xyz[((size_t)b * N_CENT + s) * 3 + 1];
    float cz = new_xyz[((size_t)b * N_CENT + s) * 3 + 2];
    float gx = Xb[id * 3 + 0] - cx;
    float gy = Xb[id * 3 + 1] - cy;
    float gz = Xb[id * 3 + 2] - cz;
    unsigned short* hrow = &h[tid * 104];
    const float4* P = (const float4*)(points + ((size_t)b * N_PTS + id) * 64);
#pragma unroll
    for (int c8 = 0; c8 < 8; ++c8) {
      float4 u = P[2 * c8], v = P[2 * c8 + 1];
      uint4 w4;
      w4.x = pkbf(u.x, u.y); w4.y = pkbf(u.z, u.w);
      w4.z = pkbf(v.x, v.y); w4.w = pkbf(v.z, v.w);
      *(uint4*)(hrow + c8 * 8) = w4;
    }
    uint4 t4;
    t4.x = pkbf(gx, gy); t4.y = pkbf(gz, 0.0f); t4.z = 0u; t4.w = 0u;
    *(uint4*)(hrow + 64) = t4;
    uint4 z4; z4.x = z4.y = z4.z = z4.w = 0u;
    *(uint4*)(hrow + 72) = z4;
    *(uint4*)(hrow + 80) = z4;
    *(uint4*)(hrow + 88) = z4;
  }
  __syncthreads();

  const int lane = tid & 63, w = tid >> 6;
  const int col = lane & 15, kq = lane >> 4;
  const unsigned short* WB0 = (const unsigned short*)wsb;
  const unsigned short* WB1 = (const unsigned short*)(wsb + 12288);
  const unsigned short* WB2 = (const unsigned short*)(wsb + 20480);
  const float* Bf0 = (const float*)(wsb + 36864);
  const float* Bf1 = (const float*)(wsb + 37120);
  const float* Bf2 = (const float*)(wsb + 37376);

  // ---- layer 1: K=96 (3 chunks), N=64 (wave w owns o = w*16..w*16+15) ----
  {
    const int o = w * 16 + col;
    float bias = Bf0[o];
    floatx4 acc[16];
#pragma unroll
    for (int mt = 0; mt < 16; ++mt) acc[mt] = floatx4{bias, bias, bias, bias};
#pragma unroll
    for (int c = 0; c < 3; ++c) {
      short8 bf = *(const short8*)(WB0 + o * 96 + kq * 8 + 32 * c);
#pragma unroll
      for (int mt = 0; mt < 16; ++mt) {
        short8 af = *(const short8*)(&h[(mt * 16 + col) * 104 + kq * 8 + 32 * c]);
        acc[mt] = __builtin_amdgcn_mfma_f32_16x16x32_bf16(af, bf, acc[mt], 0, 0, 0);
      }
    }
    __syncthreads();  // all A-reads done before overwrite
#pragma unroll
    for (int mt = 0; mt < 16; ++mt)
#pragma unroll
      for (int r = 0; r < 4; ++r)
        h[(mt * 16 + kq * 4 + r) * 104 + o] = bf1(fmaxf(acc[mt][r], 0.0f));
    __syncthreads();
  }

  // ---- layer 2: K=64 (2 chunks), N=64 ----
  {
    const int o = w * 16 + col;
    float bias = Bf1[o];
    floatx4 acc[16];
#pragma unroll
    for (int mt = 0; mt < 16; ++mt) acc[mt] = floatx4{bias, bias, bias, bias};
#pragma unroll
    for (int c = 0; c < 2; ++c) {
      short8 bf = *(const short8*)(WB1 + o * 64 + kq * 8 + 32 * c);
#pragma unroll
      for (int mt = 0; mt < 16; ++mt) {
        short8 af = *(const short8*)(&h[(mt * 16 + col) * 104 + kq * 8 + 32 * c]);
        acc[mt] = __builtin_amdgcn_mfma_f32_16x16x32_bf16(af, bf, acc[mt], 0, 0, 0);
      }
    }
    __syncthreads();
#pragma unroll
    for (int mt = 0; mt < 16; ++mt)
#pragma unroll
      for (int r = 0; r < 4; ++r)
        h[(mt * 16 + kq * 4 + r) * 104 + o] = bf1(fmaxf(acc[mt][r], 0.0f));
    __syncthreads();
  }

  // ---- layer 3: K=64, N=128 (wave w owns o = w*32..w*32+31) + maxpool ----
  {
    const int oA = w * 32 + col;
    const int oB = oA + 16;
    float biasA = Bf2[oA], biasB = Bf2[oB];
    floatx4 accA[16], accB[16];
#pragma unroll
    for (int mt = 0; mt < 16; ++mt) {
      accA[mt] = floatx4{biasA, biasA, biasA, biasA};
      accB[mt] = floatx4{biasB, biasB, biasB, biasB};
    }
#pragma unroll
    for (int c = 0; c < 2; ++c) {
      short8 bfA = *(const short8*)(WB2 + oA * 64 + kq * 8 + 32 * c);
      short8 bfB = *(const short8*)(WB2 + oB * 64 + kq * 8 + 32 * c);
#pragma unroll
      for (int mt = 0; mt < 16; ++mt) {
        short8 af = *(const short8*)(&h[(mt * 16 + col) * 104 + kq * 8 + 32 * c]);
        accA[mt] = __builtin_amdgcn_mfma_f32_16x16x32_bf16(af, bfA, accA[mt], 0, 0, 0);
        accB[mt] = __builtin_amdgcn_mfma_f32_16x16x32_bf16(af, bfB, accB[mt], 0, 0, 0);
      }
    }
    // maxpool over k=32 (= 2 M-tiles x {4 regs} x {4 lane-quads}) per centroid
#pragma unroll
    for (int mtp = 0; mtp < 8; ++mtp) {
      float vA = fmaxf(fmaxf(fmaxf(accA[2 * mtp][0], accA[2 * mtp + 1][0]),
                             fmaxf(accA[2 * mtp][1], accA[2 * mtp + 1][1])),
                       fmaxf(fmaxf(accA[2 * mtp][2], accA[2 * mtp + 1][2]),
                             fmaxf(accA[2 * mtp][3], accA[2 * mtp + 1][3])));
      float vB = fmaxf(fmaxf(fmaxf(accB[2 * mtp][0], accB[2 * mtp + 1][0]),
                             fmaxf(accB[2 * mtp][1], accB[2 * mtp + 1][1])),
                       fmaxf(fmaxf(accB[2 * mtp][2], accB[2 * mtp + 1][2]),
                             fmaxf(accB[2 * mtp][3], accB[2 * mtp + 1][3])));
      vA = fmaxf(vA, __shfl_xor(vA, 16)); vA = fmaxf(vA, __shfl_xor(vA, 32));
      vB = fmaxf(vB, __shfl_xor(vB, 16)); vB = fmaxf(vB, __shfl_xor(vB, 32));
      vA = fmaxf(vA, 0.0f); vB = fmaxf(vB, 0.0f);
      if (lane < 16) {
        float* op = out_pts + ((size_t)(b * N_CENT + s0 + mtp)) * 128;
        op[oA] = vA;
        op[oB] = vB;
      }
    }
  }
}

extern "C" void kernel_launch(void* const* d_in, const int* in_sizes, int n_in,
                              void* d_out, int out_size, void* d_ws, size_t ws_size,
                              hipStream_t stream) {
  const float* xyz = (const float*)d_in[0];
  const float* points = (const float*)d_in[1];
  float* out = (float*)d_out;
  float* new_xyz = out;                  // (16,1024,3)
  float* out_pts = out + 16 * 1024 * 3;  // (16,1024,128)
  unsigned char* wsb = (unsigned char*)d_ws;

  prep_kernel<<<64, 256, 0, stream>>>(
      (const float*)d_in[2], (const float*)d_in[3], (const float*)d_in[4],
      (const float*)d_in[5], (const float*)d_in[6], (const float*)d_in[7],
      (const float*)d_in[8], (const float*)d_in[9], (const float*)d_in[10],
      (const float*)d_in[11], (const float*)d_in[12], (const float*)d_in[13],
      (const float*)d_in[14], (const float*)d_in[15], (const float*)d_in[16],
      (const float*)d_in[17], (const float*)d_in[18], (const float*)d_in[19], wsb);
  fps_kernel<<<16, 512, 0, stream>>>(xyz, new_xyz);
  mlp_kernel<<<2048, 256, 0, stream>>>(xyz, points, new_xyz, wsb, out_pts);
}

// Round 8
// 798.267 us; speedup vs baseline: 1.2428x; 1.2428x over previous
//
#include <hip/hip_runtime.h>

#define N_PTS  4096
#define N_CENT 1024
#define K_S    32
#define EPSV   1e-5f

typedef __attribute__((ext_vector_type(8))) short short8;
typedef __attribute__((ext_vector_type(4))) float floatx4;
typedef __attribute__((ext_vector_type(2))) float float2v;

// Manual bf16 RNE (round-to-nearest-even), same as __float2bfloat16_rn for
// finite inputs; avoids the non-trivially-copyable __hip_bfloat162 class.
__device__ inline unsigned short bf1(float x) {
  unsigned u = __float_as_uint(x);
  u += 0x7fffu + ((u >> 16) & 1u);
  return (unsigned short)(u >> 16);
}
__device__ inline unsigned pkbf(float a, float b) {
  return (unsigned)bf1(a) | ((unsigned)bf1(b) << 16);
}

// ws byte layout:
//   0     : WB0 bf16 [64 o][96 k]   (k 0..63 = points ch, 64..66 = xyz, 67..95 = 0)
//   12288 : WB1 bf16 [64 o][64 k]
//   20480 : WB2 bf16 [128 o][64 k]
//   36864 : Bf0 f32[64]   37120: Bf1 f32[64]   37376: Bf2 f32[128]
//   65536 : nidx int[16*1024*32]  (2 MB)
__global__ void prep_kernel(const float* __restrict__ W0, const float* __restrict__ b0,
                            const float* __restrict__ g0, const float* __restrict__ be0,
                            const float* __restrict__ m0, const float* __restrict__ v0,
                            const float* __restrict__ W1, const float* __restrict__ b1,
                            const float* __restrict__ g1, const float* __restrict__ be1,
                            const float* __restrict__ m1, const float* __restrict__ v1,
                            const float* __restrict__ W2, const float* __restrict__ b2,
                            const float* __restrict__ g2, const float* __restrict__ be2,
                            const float* __restrict__ m2, const float* __restrict__ v2,
                            unsigned char* __restrict__ wsb) {
  const int stride = gridDim.x * blockDim.x;
  const int tid = blockIdx.x * blockDim.x + threadIdx.x;
  unsigned short* WB0 = (unsigned short*)wsb;
  unsigned short* WB1 = (unsigned short*)(wsb + 12288);
  unsigned short* WB2 = (unsigned short*)(wsb + 20480);
  float* Bf0 = (float*)(wsb + 36864);
  float* Bf1 = (float*)(wsb + 37120);
  float* Bf2 = (float*)(wsb + 37376);
  for (int i = tid; i < 64 * 96; i += stride) {
    int o = i / 96, k = i - o * 96;
    float s = g0[o] * rsqrtf(v0[o] + EPSV);
    float val = 0.0f;
    if (k < 64) val = W0[o * 67 + 3 + k] * s;
    else if (k < 67) val = W0[o * 67 + (k - 64)] * s;
    WB0[i] = bf1(val);
  }
  for (int i = tid; i < 64; i += stride) {
    float s = g0[i] * rsqrtf(v0[i] + EPSV);
    Bf0[i] = (b0[i] - m0[i]) * s + be0[i];
  }
  for (int i = tid; i < 64 * 64; i += stride) {
    int o = i >> 6;
    float s = g1[o] * rsqrtf(v1[o] + EPSV);
    WB1[i] = bf1(W1[i] * s);
  }
  for (int i = tid; i < 64; i += stride) {
    float s = g1[i] * rsqrtf(v1[i] + EPSV);
    Bf1[i] = (b1[i] - m1[i]) * s + be1[i];
  }
  for (int i = tid; i < 128 * 64; i += stride) {
    int o = i >> 6;
    float s = g2[o] * rsqrtf(v2[o] + EPSV);
    WB2[i] = bf1(W2[i] * s);
  }
  for (int i = tid; i < 128; i += stride) {
    float s = g2[i] * rsqrtf(v2[i] + EPSV);
    Bf2[i] = (b2[i] - m2[i]) * s + be2[i];
  }
}

// ---------------- FPS: one block (256 thr, 4 waves) per batch ----------------
// u64 key = (fp32 bits of dist << 32) | ~idx; packed-fp32 distance updates
// (v_pk_sub/mul/add are per-lane identical to scalar contract(off) ops, and
// compare order stays ascending-index -> exact same index sequence).
#define DPP_STEP(CTRL)                                                               \
  {                                                                                  \
    unsigned lo2 = (unsigned)__builtin_amdgcn_update_dpp(                            \
        0, (int)(unsigned)key, (CTRL), 0xf, 0xf, false);                             \
    unsigned hi2 = (unsigned)__builtin_amdgcn_update_dpp(                            \
        0, (int)(unsigned)(key >> 32), (CTRL), 0xf, 0xf, false);                     \
    unsigned long long nk = ((unsigned long long)hi2 << 32) | lo2;                   \
    if (nk > key) key = nk;                                                          \
  }

__launch_bounds__(256)
__global__ void fps_kernel(const float* __restrict__ xyz, float* __restrict__ new_xyz) {
#pragma clang fp contract(off)
  const int b = blockIdx.x;
  const int tid = threadIdx.x;
  const int lane = tid & 63, wv = tid >> 6;
  const float* X = xyz + (size_t)b * N_PTS * 3;
  __shared__ float lx[N_PTS], ly[N_PTS], lz[N_PTS];
  __shared__ float cent[N_CENT * 3];
  __shared__ unsigned long long rkey[2][4];
  float2v px[8], py[8], pz[8], dist[8];
#pragma unroll
  for (int j = 0; j < 16; ++j) {
    int p = j * 256 + tid;
    float x = X[p * 3 + 0], y = X[p * 3 + 1], z = X[p * 3 + 2];
    lx[p] = x; ly[p] = y; lz[p] = z;
    int t = j >> 1;
    if ((j & 1) == 0) { px[t].x = x; py[t].x = y; pz[t].x = z; dist[t].x = 1e10f; }
    else              { px[t].y = x; py[t].y = y; pz[t].y = z; dist[t].y = 1e10f; }
  }
  if (tid == 0) { cent[0] = X[0]; cent[1] = X[1]; cent[2] = X[2]; }
  __syncthreads();
  int far = 0;
  for (int i = 1; i < N_CENT; ++i) {
    float cx = lx[far], cy = ly[far], cz = lz[far];
    float2v cx2 = {cx, cx}, cy2 = {cy, cy}, cz2 = {cz, cz};
    float best = -1.0f;
    int bi = 0;
#pragma unroll
    for (int t = 0; t < 8; ++t) {
      float2v dx = px[t] - cx2, dy = py[t] - cy2, dz = pz[t] - cz2;
      float2v d2 = dx * dx + dy * dy + dz * dz;  // pk math, contract off
      float d0 = fminf(dist[t].x, d2.x); dist[t].x = d0;
      if (d0 > best) { best = d0; bi = (2 * t) * 256 + tid; }
      float d1 = fminf(dist[t].y, d2.y); dist[t].y = d1;
      if (d1 > best) { best = d1; bi = (2 * t + 1) * 256 + tid; }
    }
    unsigned long long key =
        ((unsigned long long)__float_as_uint(best) << 32) | (unsigned)(~bi);
    DPP_STEP(0x111);  // row_shr:1
    DPP_STEP(0x112);  // row_shr:2
    DPP_STEP(0x114);  // row_shr:4
    DPP_STEP(0x118);  // row_shr:8
    DPP_STEP(0x142);  // row_bcast15
    DPP_STEP(0x143);  // row_bcast31 -> lane 63 has wave winner
    const int par = i & 1;
    if (lane == 63) rkey[par][wv] = key;
    __syncthreads();
    unsigned long long k0 = rkey[par][0], k1 = rkey[par][1];
    unsigned long long k2 = rkey[par][2], k3 = rkey[par][3];
    if (k1 > k0) k0 = k1;
    if (k3 > k2) k2 = k3;
    if (k2 > k0) k0 = k2;
    far = (int)~(unsigned)k0;
    if (tid == 0) {
      cent[i * 3 + 0] = lx[far];
      cent[i * 3 + 1] = ly[far];
      cent[i * 3 + 2] = lz[far];
    }
  }
  __syncthreads();
  const size_t ob = (size_t)b * N_CENT * 3;
  for (int t = tid; t < N_CENT * 3; t += 256) new_xyz[ob + t] = cent[t];
}

// ---------------- ball query (standalone, LDS-free -> 32 waves/CU) ----------
// Each wave scans for 2 centroids interleaved; decisions bit-identical to R7.
__launch_bounds__(256)
__global__ void query_kernel(const float* __restrict__ xyz,
                             const float* __restrict__ new_xyz,
                             int* __restrict__ nid_g) {
#pragma clang fp contract(off)
  const int blk = blockIdx.x;
  const int b = blk >> 7;
  const int s0 = (blk & 127) << 3;
  const int tid = threadIdx.x;
  const int wv = tid >> 6, lane = tid & 63;
  const float* Xb = xyz + (size_t)b * N_PTS * 3;
  const float r2 = (float)(0.2 * 0.2);
  const int sA = s0 + wv * 2, sB = sA + 1;
  float cxA = new_xyz[((size_t)b * N_CENT + sA) * 3 + 0];
  float cyA = new_xyz[((size_t)b * N_CENT + sA) * 3 + 1];
  float czA = new_xyz[((size_t)b * N_CENT + sA) * 3 + 2];
  float cxB = new_xyz[((size_t)b * N_CENT + sB) * 3 + 0];
  float cyB = new_xyz[((size_t)b * N_CENT + sB) * 3 + 1];
  float czB = new_xyz[((size_t)b * N_CENT + sB) * 3 + 2];
  float scA = cxA * cxA + cyA * cyA + czA * czA;
  float scB = cxB * cxB + cyB * cyB + czB * czB;
  int* outA = nid_g + ((size_t)b * N_CENT + sA) * K_S;
  int* outB = nid_g + ((size_t)b * N_CENT + sB) * K_S;
  int cntA = 0, cntB = 0, firstA = 0, firstB = 0;
  for (int base = 0; base < N_PTS && (cntA < K_S || cntB < K_S); base += 64) {
    int p = base + lane;
    float x = Xb[p * 3 + 0], y = Xb[p * 3 + 1], z = Xb[p * 3 + 2];
    float sp = x * x + y * y + z * z;
    float dtA = __builtin_fmaf(czA, z, __builtin_fmaf(cyA, y, cxA * x));
    float dtB = __builtin_fmaf(czB, z, __builtin_fmaf(cyB, y, cxB * x));
    float d2A = (scA + sp) - 2.0f * dtA;
    float d2B = (scB + sp) - 2.0f * dtB;
    bool inA = !(d2A > r2);
    bool inB = !(d2B > r2);
    unsigned long long mA = __ballot(inA);
    unsigned long long mB = __ballot(inB);
    if (cntA == 0 && mA != 0ull) firstA = base + __builtin_ctzll(mA);
    if (cntB == 0 && mB != 0ull) firstB = base + __builtin_ctzll(mB);
    unsigned long long below = (1ull << lane) - 1ull;
    int posA = cntA + __popcll(mA & below);
    int posB = cntB + __popcll(mB & below);
    if (inA && posA < K_S) outA[posA] = p;
    if (inB && posB < K_S) outB[posB] = p;
    cntA += __popcll(mA);
    cntB += __popcll(mB);
  }
  if (cntA < K_S)
    for (int j = cntA + lane; j < K_S; j += 64) outA[j] = firstA;
  if (cntB < K_S)
    for (int j = cntB + lane; j < K_S; j += 64) outB[j] = firstB;
}

// ------- gather + 3-layer bf16-MFMA MLP + maxpool -------
// 256 thr = 4 waves; 8 centroids x 32 samples = 256 points per block.
// h LDS rows: 96 bf16 K-channels (+8 pad) = 208 B stride.
__launch_bounds__(256)
__global__ void mlp_kernel(const float* __restrict__ xyz,
                           const float* __restrict__ points,
                           const float* __restrict__ new_xyz,
                           const unsigned char* __restrict__ wsb,
                           const int* __restrict__ nid_g,
                           float* __restrict__ out_pts) {
  __shared__ __align__(16) unsigned short h[256 * 104];
  const int blk = blockIdx.x;
  const int b = blk >> 7;
  const int s0 = (blk & 127) << 3;
  const int tid = threadIdx.x;
  const float* Xb = xyz + (size_t)b * N_PTS * 3;

  // ---- gather -> h rows (bf16): k0..63 = points, 64..66 = xyz-norm, rest 0
  {
    const int s = s0 + (tid >> 5);
    const int id = nid_g[((size_t)b * N_CENT + s0) * K_S + tid];  // coalesced
    float cx = new_xyz[((size_t)b * N_CENT + s) * 3 + 0];
    float cy = new_xyz[((size_t)b * N_CENT + s) * 3 + 1];
    float cz = new_xyz[((size_t)b * N_CENT + s) * 3 + 2];
    float gx = Xb[id * 3 + 0] - cx;
    float gy = Xb[id * 3 + 1] - cy;
    float gz = Xb[id * 3 + 2] - cz;
    unsigned short* hrow = &h[tid * 104];
    const float4* P = (const float4*)(points + ((size_t)b * N_PTS + id) * 64);
#pragma unroll
    for (int c8 = 0; c8 < 8; ++c8) {
      float4 u = P[2 * c8], v = P[2 * c8 + 1];
      uint4 w4;
      w4.x = pkbf(u.x, u.y); w4.y = pkbf(u.z, u.w);
      w4.z = pkbf(v.x, v.y); w4.w = pkbf(v.z, v.w);
      *(uint4*)(hrow + c8 * 8) = w4;
    }
    uint4 t4;
    t4.x = pkbf(gx, gy); t4.y = pkbf(gz, 0.0f); t4.z = 0u; t4.w = 0u;
    *(uint4*)(hrow + 64) = t4;
    uint4 z4; z4.x = z4.y = z4.z = z4.w = 0u;
    *(uint4*)(hrow + 72) = z4;
    *(uint4*)(hrow + 80) = z4;
    *(uint4*)(hrow + 88) = z4;
  }
  __syncthreads();

  const int lane = tid & 63, w = tid >> 6;
  const int col = lane & 15, kq = lane >> 4;
  const unsigned short* WB0 = (const unsigned short*)wsb;
  const unsigned short* WB1 = (const unsigned short*)(wsb + 12288);
  const unsigned short* WB2 = (const unsigned short*)(wsb + 20480);
  const float* Bf0 = (const float*)(wsb + 36864);
  const float* Bf1 = (const float*)(wsb + 37120);
  const float* Bf2 = (const float*)(wsb + 37376);

  // ---- layer 1: K=96 (3 chunks), N=64 (wave w owns o = w*16..w*16+15) ----
  {
    const int o = w * 16 + col;
    float bias = Bf0[o];
    floatx4 acc[16];
#pragma unroll
    for (int mt = 0; mt < 16; ++mt) acc[mt] = floatx4{bias, bias, bias, bias};
#pragma unroll
    for (int c = 0; c < 3; ++c) {
      short8 bf = *(const short8*)(WB0 + o * 96 + kq * 8 + 32 * c);
#pragma unroll
      for (int mt = 0; mt < 16; ++mt) {
        short8 af = *(const short8*)(&h[(mt * 16 + col) * 104 + kq * 8 + 32 * c]);
        acc[mt] = __builtin_amdgcn_mfma_f32_16x16x32_bf16(af, bf, acc[mt], 0, 0, 0);
      }
    }
    __syncthreads();  // all A-reads done before overwrite
#pragma unroll
    for (int mt = 0; mt < 16; ++mt)
#pragma unroll
      for (int r = 0; r < 4; ++r)
        h[(mt * 16 + kq * 4 + r) * 104 + o] = bf1(fmaxf(acc[mt][r], 0.0f));
    __syncthreads();
  }

  // ---- layer 2: K=64 (2 chunks), N=64 ----
  {
    const int o = w * 16 + col;
    float bias = Bf1[o];
    floatx4 acc[16];
#pragma unroll
    for (int mt = 0; mt < 16; ++mt) acc[mt] = floatx4{bias, bias, bias, bias};
#pragma unroll
    for (int c = 0; c < 2; ++c) {
      short8 bf = *(const short8*)(WB1 + o * 64 + kq * 8 + 32 * c);
#pragma unroll
      for (int mt = 0; mt < 16; ++mt) {
        short8 af = *(const short8*)(&h[(mt * 16 + col) * 104 + kq * 8 + 32 * c]);
        acc[mt] = __builtin_amdgcn_mfma_f32_16x16x32_bf16(af, bf, acc[mt], 0, 0, 0);
      }
    }
    __syncthreads();
#pragma unroll
    for (int mt = 0; mt < 16; ++mt)
#pragma unroll
      for (int r = 0; r < 4; ++r)
        h[(mt * 16 + kq * 4 + r) * 104 + o] = bf1(fmaxf(acc[mt][r], 0.0f));
    __syncthreads();
  }

  // ---- layer 3: K=64, N=128 (wave w owns o = w*32..w*32+31) + maxpool ----
  {
    const int oA = w * 32 + col;
    const int oB = oA + 16;
    float biasA = Bf2[oA], biasB = Bf2[oB];
    floatx4 accA[16], accB[16];
#pragma unroll
    for (int mt = 0; mt < 16; ++mt) {
      accA[mt] = floatx4{biasA, biasA, biasA, biasA};
      accB[mt] = floatx4{biasB, biasB, biasB, biasB};
    }
#pragma unroll
    for (int c = 0; c < 2; ++c) {
      short8 bfA = *(const short8*)(WB2 + oA * 64 + kq * 8 + 32 * c);
      short8 bfB = *(const short8*)(WB2 + oB * 64 + kq * 8 + 32 * c);
#pragma unroll
      for (int mt = 0; mt < 16; ++mt) {
        short8 af = *(const short8*)(&h[(mt * 16 + col) * 104 + kq * 8 + 32 * c]);
        accA[mt] = __builtin_amdgcn_mfma_f32_16x16x32_bf16(af, bfA, accA[mt], 0, 0, 0);
        accB[mt] = __builtin_amdgcn_mfma_f32_16x16x32_bf16(af, bfB, accB[mt], 0, 0, 0);
      }
    }
    // maxpool over k=32 (= 2 M-tiles x {4 regs} x {4 lane-quads}) per centroid
#pragma unroll
    for (int mtp = 0; mtp < 8; ++mtp) {
      float vA = fmaxf(fmaxf(fmaxf(accA[2 * mtp][0], accA[2 * mtp + 1][0]),
                             fmaxf(accA[2 * mtp][1], accA[2 * mtp + 1][1])),
                       fmaxf(fmaxf(accA[2 * mtp][2], accA[2 * mtp + 1][2]),
                             fmaxf(accA[2 * mtp][3], accA[2 * mtp + 1][3])));
      float vB = fmaxf(fmaxf(fmaxf(accB[2 * mtp][0], accB[2 * mtp + 1][0]),
                             fmaxf(accB[2 * mtp][1], accB[2 * mtp + 1][1])),
                       fmaxf(fmaxf(accB[2 * mtp][2], accB[2 * mtp + 1][2]),
                             fmaxf(accB[2 * mtp][3], accB[2 * mtp + 1][3])));
      vA = fmaxf(vA, __shfl_xor(vA, 16)); vA = fmaxf(vA, __shfl_xor(vA, 32));
      vB = fmaxf(vB, __shfl_xor(vB, 16)); vB = fmaxf(vB, __shfl_xor(vB, 32));
      vA = fmaxf(vA, 0.0f); vB = fmaxf(vB, 0.0f);
      if (lane < 16) {
        float* op = out_pts + ((size_t)(b * N_CENT + s0 + mtp)) * 128;
        op[oA] = vA;
        op[oB] = vB;
      }
    }
  }
}

extern "C" void kernel_launch(void* const* d_in, const int* in_sizes, int n_in,
                              void* d_out, int out_size, void* d_ws, size_t ws_size,
                              hipStream_t stream) {
  const float* xyz = (const float*)d_in[0];
  const float* points = (const float*)d_in[1];
  float* out = (float*)d_out;
  float* new_xyz = out;                  // (16,1024,3)
  float* out_pts = out + 16 * 1024 * 3;  // (16,1024,128)
  unsigned char* wsb = (unsigned char*)d_ws;
  int* nid_g = (int*)(wsb + 65536);

  prep_kernel<<<64, 256, 0, stream>>>(
      (const float*)d_in[2], (const float*)d_in[3], (const float*)d_in[4],
      (const float*)d_in[5], (const float*)d_in[6], (const float*)d_in[7],
      (const float*)d_in[8], (const float*)d_in[9], (const float*)d_in[10],
      (const float*)d_in[11], (const float*)d_in[12], (const float*)d_in[13],
      (const float*)d_in[14], (const float*)d_in[15], (const float*)d_in[16],
      (const float*)d_in[17], (const float*)d_in[18], (const float*)d_in[19], wsb);
  fps_kernel<<<16, 256, 0, stream>>>(xyz, new_xyz);
  query_kernel<<<2048, 256, 0, stream>>>(xyz, new_xyz, nid_g);
  mlp_kernel<<<2048, 256, 0, stream>>>(xyz, points, new_xyz, wsb, nid_g, out_pts);
}